// Round 5
// baseline (673.684 us; speedup 1.0000x reference)
//
#include <hip/hip_runtime.h>

#define N_NODES 50000
#define N_EDGES 600000
#define D 128
#define NLAYERS 5
#define EPS 1e-5f
#define GX_BLOCKS 782  // (N_NODES + 63) / 64

typedef _Float16 f16;
typedef f16 f16x8 __attribute__((ext_vector_type(8)));
typedef f16 f16x4 __attribute__((ext_vector_type(4)));
typedef f16 f16x2 __attribute__((ext_vector_type(2)));
typedef float f32x4 __attribute__((ext_vector_type(4)));

// ---------------- CSR build ----------------

__global__ void deg_kernel(const int* __restrict__ dst, int* __restrict__ deg) {
    int e = blockIdx.x * blockDim.x + threadIdx.x;
    if (e < N_EDGES) atomicAdd(&deg[dst[e]], 1);
}

__global__ __launch_bounds__(1024) void scan_block_kernel(const int* __restrict__ deg,
                                                          int* __restrict__ offsets,
                                                          int* __restrict__ blocksums) {
    __shared__ int tmp[1024];
    int i = blockIdx.x * 1024 + threadIdx.x;
    int v = (i < N_NODES) ? deg[i] : 0;
    tmp[threadIdx.x] = v;
    __syncthreads();
#pragma unroll
    for (int off = 1; off < 1024; off <<= 1) {
        int t = (threadIdx.x >= off) ? tmp[threadIdx.x - off] : 0;
        __syncthreads();
        tmp[threadIdx.x] += t;
        __syncthreads();
    }
    if (i < N_NODES) offsets[i] = tmp[threadIdx.x] - v;  // exclusive
    if (threadIdx.x == 1023) blocksums[blockIdx.x] = tmp[1023];
}

__global__ void scan_sums_kernel(int* __restrict__ blocksums, int nb, int* __restrict__ offsets) {
    if (threadIdx.x == 0 && blockIdx.x == 0) {
        int run = 0;
        for (int i = 0; i < nb; ++i) {
            int t = blocksums[i];
            blocksums[i] = run;
            run += t;
        }
        offsets[N_NODES] = N_EDGES;
    }
}

__global__ __launch_bounds__(1024) void scan_add_kernel(int* __restrict__ offsets,
                                                        const int* __restrict__ blocksums) {
    int i = blockIdx.x * 1024 + threadIdx.x;
    if (i < N_NODES) offsets[i] += blocksums[blockIdx.x];
}

__global__ void scatter_kernel(const int* __restrict__ src, const int* __restrict__ dst,
                               int* __restrict__ cursor, int* __restrict__ sorted_src) {
    int e = blockIdx.x * blockDim.x + threadIdx.x;
    if (e >= N_EDGES) return;
    int t = dst[e];
    int pos = atomicAdd(&cursor[t], 1);
    sorted_src[pos] = src[e];
}

// ---------------- weight convert to MFMA fragment order ----------------
// w1f: per layer [cb=16][kk=4][lane=64][e=8];  n = cb*16+(lane&15), k = kk*32+(lane>>4)*8+e
// w2f: per layer [cb=8 ][kk=8][lane=64][e=8];  n = cb*16+(lane&15), k = kk*32+(lane>>4)*8+e
__global__ void convert_w_kernel(const float* __restrict__ W1, const float* __restrict__ W2,
                                 f16* __restrict__ w1f, f16* __restrict__ w2f) {
    int idx = blockIdx.x * blockDim.x + threadIdx.x;
    if (idx >= NLAYERS * 32768) return;
    int l = idx >> 15, rem = idx & 32767;
    {
        int e = rem & 7, lane = (rem >> 3) & 63, kk = (rem >> 9) & 3, cb = rem >> 11;
        int n = cb * 16 + (lane & 15);
        int k = kk * 32 + (lane >> 4) * 8 + e;
        w1f[idx] = (f16)W1[((size_t)l * D + k) * (2 * D) + n];
    }
    {
        int e = rem & 7, lane = (rem >> 3) & 63, kk = (rem >> 9) & 7, cb = rem >> 12;
        int n = cb * 16 + (lane & 15);
        int k = kk * 32 + (lane >> 4) * 8 + e;
        w2f[idx] = (f16)W2[((size_t)l * 2 * D + k) * D + n];
    }
}

// ---------------- model kernels ----------------

__global__ void embed_kernel(const int* __restrict__ x, const float* __restrict__ emb,
                             f16* __restrict__ h_h) {
    int idx = blockIdx.x * blockDim.x + threadIdx.x;  // one 8-elem chunk
    if (idx >= N_NODES * (D / 8)) return;
    int n = idx >> 4;   // D/8 = 16
    int d8 = idx & 15;
    const float* e = emb + x[n] * D + d8 * 8;
    f16x8 v;
#pragma unroll
    for (int j = 0; j < 8; ++j) v[j] = (f16)e[j];
    *(f16x8*)(h_h + (size_t)n * D + d8 * 8) = v;
}

// pull aggregation: agg_h[n] = (f16)( h_h[n] + sum_{s in in(n)} h_h[s] ), fp32 accum
__global__ __launch_bounds__(256) void agg_kernel(const int* __restrict__ offsets,
                                                  const int* __restrict__ sorted_src,
                                                  const f16* __restrict__ h_h,
                                                  f16* __restrict__ agg_h) {
    int node = blockIdx.x * 4 + (threadIdx.x >> 6);
    if (node >= N_NODES) return;
    int lane = threadIdx.x & 63;
    f16x2 hv = *(const f16x2*)(h_h + (size_t)node * D + lane * 2);
    float sx = (float)hv[0], sy = (float)hv[1];  // self loop
    int j = offsets[node];
    const int end = offsets[node + 1];
    for (; j + 4 <= end; j += 4) {
        int s0 = sorted_src[j + 0];
        int s1 = sorted_src[j + 1];
        int s2 = sorted_src[j + 2];
        int s3 = sorted_src[j + 3];
        f16x2 a = *(const f16x2*)(h_h + (size_t)s0 * D + lane * 2);
        f16x2 b = *(const f16x2*)(h_h + (size_t)s1 * D + lane * 2);
        f16x2 c = *(const f16x2*)(h_h + (size_t)s2 * D + lane * 2);
        f16x2 d = *(const f16x2*)(h_h + (size_t)s3 * D + lane * 2);
        sx += (float)a[0] + (float)b[0] + (float)c[0] + (float)d[0];
        sy += (float)a[1] + (float)b[1] + (float)c[1] + (float)d[1];
    }
    for (; j < end; ++j) {
        f16x2 a = *(const f16x2*)(h_h + (size_t)sorted_src[j] * D + lane * 2);
        sx += (float)a[0];
        sy += (float)a[1];
    }
    f16x2 o;
    o[0] = (f16)sx;
    o[1] = (f16)sy;
    *(f16x2*)(agg_h + (size_t)node * D + lane * 2) = o;
}

__device__ __forceinline__ void gload_lds16(const void* g, void* l) {
    __builtin_amdgcn_global_load_lds((const __attribute__((address_space(1))) void*)g,
                                     (__attribute__((address_space(3))) void*)l, 16, 0, 0);
}

// Fused GIN MLP: z2 = (relu(agg @ W1 + b1)) @ W2 + b2 (stored f16), block-partial column
// stats (sum, sumsq) written contiguously to partial[blockIdx][256] — NO global atomics.
__global__ __launch_bounds__(256) void fused_mlp(const f16* __restrict__ A,
                                                 const f16* __restrict__ w1f,
                                                 const float* __restrict__ b1,
                                                 const f16* __restrict__ w2f,
                                                 const float* __restrict__ b2,
                                                 f16* __restrict__ z2h,
                                                 float* __restrict__ partial) {
    __shared__ __align__(16) char smem[32768 + 1024];
    f16* As = (f16*)smem;                   // 64 x 128 halfs, swizzled (16 KB), aliased by z1s
    f16* z1s = (f16*)smem;                  // 64 x 256 halfs, swizzled (32 KB)
    float* sred = (float*)(smem + 32768);   // 256 f32

    const int tid = threadIdx.x;
    const int r0 = blockIdx.x * 64;
    const int lane = tid & 63;
    const int wave = tid >> 6;
    const int wr = wave >> 1, wc = wave & 1;
    const int l15 = lane & 15, l4 = lane >> 4;

    for (int i = tid; i < 256; i += 256) sred[i] = 0.f;

    // ---- stage A tile: global_load_lds, linear LDS dest + pre-swizzled global source ----
#pragma unroll
    for (int it = 0; it < 4; ++it) {
        const int idx = it * 256 + tid;
        const int row = idx >> 4, c = idx & 15;
        const char* gsrc = (const char*)(A + (size_t)(r0 + row) * D) + ((c * 16) ^ ((row & 7) << 4));
        gload_lds16(gsrc, (char*)As + idx * 16);
    }
    __syncthreads();

    // ---- stage 1: z1^T via mfma(W1, A). lane holds z1[m=l15][n=cf*16+l4*4+j] ----
    f32x4 acc1[2][8] = {};
#pragma unroll
    for (int kk = 0; kk < 4; ++kk) {
        f16x8 afr[2];
#pragma unroll
        for (int fm = 0; fm < 2; ++fm) {
            const int m = wr * 32 + fm * 16 + l15;
            const int byte = ((m * D + kk * 32 + l4 * 8) * 2) ^ ((m & 7) << 4);
            afr[fm] = *(const f16x8*)((const char*)As + byte);
        }
#pragma unroll
        for (int cf = 0; cf < 8; ++cf) {
            f16x8 w = *(const f16x8*)(w1f + ((((wc * 8 + cf) * 4) + kk) * 64 + lane) * 8);
#pragma unroll
            for (int fm = 0; fm < 2; ++fm)
                acc1[fm][cf] = __builtin_amdgcn_mfma_f32_16x16x32_f16(w, afr[fm], acc1[fm][cf], 0, 0, 0);
        }
    }
    __syncthreads();  // all As reads complete before overwriting with z1s

    // ---- epilogue 1: bias + relu -> f16 -> z1s (contiguous 8B writes, swizzled) ----
#pragma unroll
    for (int fm = 0; fm < 2; ++fm) {
        const int m = wr * 32 + fm * 16 + l15;
#pragma unroll
        for (int cf = 0; cf < 8; ++cf) {
            const int n = wc * 128 + cf * 16 + l4 * 4;
            const float4 bb = *(const float4*)(b1 + n);
            f16x4 v;
            v[0] = (f16)fmaxf(acc1[fm][cf][0] + bb.x, 0.f);
            v[1] = (f16)fmaxf(acc1[fm][cf][1] + bb.y, 0.f);
            v[2] = (f16)fmaxf(acc1[fm][cf][2] + bb.z, 0.f);
            v[3] = (f16)fmaxf(acc1[fm][cf][3] + bb.w, 0.f);
            const int byte = ((m * 256 + n) * 2) ^ ((m & 7) << 4);
            *(f16x4*)((char*)z1s + byte) = v;
        }
    }
    __syncthreads();

    // ---- stage 2: z2 = z1 @ W2 (non-swapped), 2x4 frags per wave ----
    f32x4 acc2[2][4] = {};
#pragma unroll
    for (int kk = 0; kk < 8; ++kk) {
        f16x8 afr[2];
#pragma unroll
        for (int fm = 0; fm < 2; ++fm) {
            const int m = wr * 32 + fm * 16 + l15;
            const int byte = ((m * 256 + kk * 32 + l4 * 8) * 2) ^ ((m & 7) << 4);
            afr[fm] = *(const f16x8*)((const char*)z1s + byte);
        }
#pragma unroll
        for (int cf = 0; cf < 4; ++cf) {
            f16x8 w = *(const f16x8*)(w2f + ((((wc * 4 + cf) * 8) + kk) * 64 + lane) * 8);
#pragma unroll
            for (int fm = 0; fm < 2; ++fm)
                acc2[fm][cf] = __builtin_amdgcn_mfma_f32_16x16x32_f16(afr[fm], w, acc2[fm][cf], 0, 0, 0);
        }
    }

    // ---- epilogue 2: bias, store f16, column partial stats ----
    float bv[4];
#pragma unroll
    for (int cf = 0; cf < 4; ++cf) bv[cf] = b2[wc * 64 + cf * 16 + l15];

    float cs[4], cq[4];
#pragma unroll
    for (int cf = 0; cf < 4; ++cf) { cs[cf] = 0.f; cq[cf] = 0.f; }
#pragma unroll
    for (int fm = 0; fm < 2; ++fm)
#pragma unroll
        for (int cf = 0; cf < 4; ++cf) {
            const int col = wc * 64 + cf * 16 + l15;
#pragma unroll
            for (int j = 0; j < 4; ++j) {
                const int row = r0 + wr * 32 + fm * 16 + l4 * 4 + j;
                if (row < N_NODES) {
                    float z = acc2[fm][cf][j] + bv[cf];
                    z2h[(size_t)row * D + col] = (f16)z;
                    cs[cf] += z;
                    cq[cf] += z * z;
                }
            }
        }
#pragma unroll
    for (int cf = 0; cf < 4; ++cf) {
        float s = cs[cf], q = cq[cf];
        s += __shfl_xor(s, 16, 64);
        q += __shfl_xor(q, 16, 64);
        s += __shfl_xor(s, 32, 64);
        q += __shfl_xor(q, 32, 64);
        if (l4 == 0) {
            const int col = wc * 64 + cf * 16 + l15;
            atomicAdd(&sred[col], s);        // LDS atomics only (4 waves)
            atomicAdd(&sred[D + col], q);
        }
    }
    __syncthreads();
    // contiguous, contention-free partial write (1 KB per block)
    for (int i = tid; i < 256; i += 256) partial[(size_t)blockIdx.x * 256 + i] = sred[i];
}

// deterministic stats reduce: stats[c] = sum_b partial[b][c]
__global__ __launch_bounds__(1024) void reduce_stats_kernel(const float* __restrict__ partial,
                                                            float* __restrict__ stats) {
    __shared__ float red[4][256];
    const int c = threadIdx.x & 255, q = threadIdx.x >> 8;
    float s = 0.f;
    for (int b = q; b < GX_BLOCKS; b += 4) s += partial[(size_t)b * 256 + c];
    red[q][c] = s;
    __syncthreads();
    if (q == 0) stats[c] = red[0][c] + red[1][c] + red[2][c] + red[3][c];
}

// BatchNorm (training stats); !LAST: relu -> h_h (f16). LAST: no relu -> h (f32, d_out).
template <bool LAST>
__global__ void bn_kernel(const f16* __restrict__ z, const float* __restrict__ stats,
                          const float* __restrict__ gamma, const float* __restrict__ beta,
                          float* __restrict__ hout, f16* __restrict__ h_h) {
    int idx = blockIdx.x * blockDim.x + threadIdx.x;  // one f16x4 chunk
    if (idx >= N_NODES * (D / 4)) return;
    int d4 = idx & 31;
    f16x4 zv = *(const f16x4*)(z + (size_t)idx * 4);
    float4 s = *(const float4*)(stats + d4 * 4);
    float4 sq = *(const float4*)(stats + D + d4 * 4);
    float4 g = *(const float4*)(gamma + d4 * 4);
    float4 b = *(const float4*)(beta + d4 * 4);
    const float invN = 1.0f / (float)N_NODES;
    float ss[4] = {s.x, s.y, s.z, s.w};
    float qq[4] = {sq.x, sq.y, sq.z, sq.w};
    float gg[4] = {g.x, g.y, g.z, g.w};
    float bb[4] = {b.x, b.y, b.z, b.w};
    float o[4];
#pragma unroll
    for (int j = 0; j < 4; ++j) {
        float m = ss[j] * invN;
        float var = qq[j] * invN - m * m;
        float r = rsqrtf(var + EPS);
        o[j] = gg[j] * ((float)zv[j] - m) * r + bb[j];
    }
    if constexpr (LAST) {
        *(float4*)(hout + (size_t)idx * 4) = make_float4(o[0], o[1], o[2], o[3]);
    } else {
        f16x4 v;
#pragma unroll
        for (int j = 0; j < 4; ++j) v[j] = (f16)fmaxf(o[j], 0.f);
        *(f16x4*)(h_h + (size_t)idx * 4) = v;
    }
}

extern "C" void kernel_launch(void* const* d_in, const int* in_sizes, int n_in,
                              void* d_out, int out_size, void* d_ws, size_t ws_size,
                              hipStream_t stream) {
    const int* x_nodes = (const int*)d_in[0];
    const int* src = (const int*)d_in[1];
    const int* dst = (const int*)d_in[2];
    const float* emb = (const float*)d_in[3];
    const float* W1 = (const float*)d_in[4];
    const float* b1 = (const float*)d_in[5];
    const float* W2 = (const float*)d_in[6];
    const float* b2 = (const float*)d_in[7];
    const float* gamma = (const float*)d_in[8];
    const float* beta = (const float*)d_in[9];

    float* h = (float*)d_out;  // final fp32 output

    // workspace layout
    f16* z2h = (f16*)d_ws;                                      // N*D f16
    f16* agg_h = z2h + (size_t)N_NODES * D;                     // N*D f16
    f16* h_h = agg_h + (size_t)N_NODES * D;                     // N*D f16
    f16* w1f = h_h + (size_t)N_NODES * D;                       // L*32768 f16
    f16* w2f = w1f + (size_t)NLAYERS * 2 * D * D;               // L*32768 f16
    float* stats = (float*)(w2f + (size_t)NLAYERS * 2 * D * D); // 256 f32
    float* partial = stats + 256;                               // GX_BLOCKS*256 f32
    int* deg = (int*)(partial + (size_t)GX_BLOCKS * 256);       // N
    int* offsets = deg + N_NODES;                               // N+1
    int* cursor = offsets + N_NODES + 1;                        // N
    int* blocksums = cursor + N_NODES;                          // 64
    int* sorted_src = blocksums + 64;                           // E

    dim3 blk(256);
    const int nb_scan = (N_NODES + 1023) / 1024;  // 49
    const int nb_edge = (N_EDGES + 255) / 256;

    // ---- one-time per call: weights + CSR ----
    convert_w_kernel<<<(NLAYERS * 32768 + 255) / 256, blk, 0, stream>>>(W1, W2, w1f, w2f);
    hipMemsetAsync(deg, 0, N_NODES * sizeof(int), stream);
    deg_kernel<<<nb_edge, blk, 0, stream>>>(dst, deg);
    scan_block_kernel<<<nb_scan, 1024, 0, stream>>>(deg, offsets, blocksums);
    scan_sums_kernel<<<1, 64, 0, stream>>>(blocksums, nb_scan, offsets);
    scan_add_kernel<<<nb_scan, 1024, 0, stream>>>(offsets, blocksums);
    hipMemcpyAsync(cursor, offsets, N_NODES * sizeof(int), hipMemcpyDeviceToDevice, stream);
    scatter_kernel<<<nb_edge, blk, 0, stream>>>(src, dst, cursor, sorted_src);

    // ---- model ----
    embed_kernel<<<(N_NODES * 16 + 255) / 256, blk, 0, stream>>>(x_nodes, emb, h_h);

    for (int l = 0; l < NLAYERS; ++l) {
        agg_kernel<<<(N_NODES + 3) / 4, blk, 0, stream>>>(offsets, sorted_src, h_h, agg_h);
        fused_mlp<<<GX_BLOCKS, blk, 0, stream>>>(agg_h, w1f + (size_t)l * 32768, b1 + l * 2 * D,
                                                 w2f + (size_t)l * 32768, b2 + l * D, z2h, partial);
        reduce_stats_kernel<<<1, 1024, 0, stream>>>(partial, stats);
        if (l < NLAYERS - 1) {
            bn_kernel<false><<<(N_NODES * 32 + 255) / 256, blk, 0, stream>>>(
                z2h, stats, gamma + l * D, beta + l * D, nullptr, h_h);
        } else {
            bn_kernel<true><<<(N_NODES * 32 + 255) / 256, blk, 0, stream>>>(
                z2h, stats, gamma + l * D, beta + l * D, h, nullptr);
        }
    }
    (void)in_sizes; (void)n_in; (void)out_size; (void)ws_size;
}

// Round 6
// 454.645 us; speedup vs baseline: 1.4818x; 1.4818x over previous
//
#include <hip/hip_runtime.h>

#define N_NODES 50000
#define N_EDGES 600000
#define D 128
#define NLAYERS 5
#define EPS 1e-5f
#define GX_BLOCKS 782  // (N_NODES + 63) / 64
#define NB_RED 32      // stage-1 reduce blocks

typedef _Float16 f16;
typedef f16 f16x8 __attribute__((ext_vector_type(8)));
typedef f16 f16x4 __attribute__((ext_vector_type(4)));
typedef f16 f16x2 __attribute__((ext_vector_type(2)));
typedef float f32x4 __attribute__((ext_vector_type(4)));

// ---------------- CSR build ----------------

__global__ void deg_kernel(const int* __restrict__ dst, int* __restrict__ deg) {
    int e = blockIdx.x * blockDim.x + threadIdx.x;
    if (e < N_EDGES) atomicAdd(&deg[dst[e]], 1);
}

__global__ __launch_bounds__(1024) void scan_block_kernel(const int* __restrict__ deg,
                                                          int* __restrict__ offsets,
                                                          int* __restrict__ blocksums) {
    __shared__ int tmp[1024];
    int i = blockIdx.x * 1024 + threadIdx.x;
    int v = (i < N_NODES) ? deg[i] : 0;
    tmp[threadIdx.x] = v;
    __syncthreads();
#pragma unroll
    for (int off = 1; off < 1024; off <<= 1) {
        int t = (threadIdx.x >= off) ? tmp[threadIdx.x - off] : 0;
        __syncthreads();
        tmp[threadIdx.x] += t;
        __syncthreads();
    }
    if (i < N_NODES) offsets[i] = tmp[threadIdx.x] - v;  // exclusive
    if (threadIdx.x == 1023) blocksums[blockIdx.x] = tmp[1023];
}

__global__ void scan_sums_kernel(int* __restrict__ blocksums, int nb, int* __restrict__ offsets) {
    if (threadIdx.x == 0 && blockIdx.x == 0) {
        int run = 0;
        for (int i = 0; i < nb; ++i) {
            int t = blocksums[i];
            blocksums[i] = run;
            run += t;
        }
        offsets[N_NODES] = N_EDGES;
    }
}

__global__ __launch_bounds__(1024) void scan_add_kernel(int* __restrict__ offsets,
                                                        const int* __restrict__ blocksums) {
    int i = blockIdx.x * 1024 + threadIdx.x;
    if (i < N_NODES) offsets[i] += blocksums[blockIdx.x];
}

__global__ void scatter_kernel(const int* __restrict__ src, const int* __restrict__ dst,
                               int* __restrict__ cursor, int* __restrict__ sorted_src) {
    int e = blockIdx.x * blockDim.x + threadIdx.x;
    if (e >= N_EDGES) return;
    int t = dst[e];
    int pos = atomicAdd(&cursor[t], 1);
    sorted_src[pos] = src[e];
}

// ---------------- weight convert to MFMA fragment order ----------------
// w1f: per layer [cb=16][kk=4][lane=64][e=8];  n = cb*16+(lane&15), k = kk*32+(lane>>4)*8+e
// w2f: per layer [cb=8 ][kk=8][lane=64][e=8];  n = cb*16+(lane&15), k = kk*32+(lane>>4)*8+e
__global__ void convert_w_kernel(const float* __restrict__ W1, const float* __restrict__ W2,
                                 f16* __restrict__ w1f, f16* __restrict__ w2f) {
    int idx = blockIdx.x * blockDim.x + threadIdx.x;
    if (idx >= NLAYERS * 32768) return;
    int l = idx >> 15, rem = idx & 32767;
    {
        int e = rem & 7, lane = (rem >> 3) & 63, kk = (rem >> 9) & 3, cb = rem >> 11;
        int n = cb * 16 + (lane & 15);
        int k = kk * 32 + (lane >> 4) * 8 + e;
        w1f[idx] = (f16)W1[((size_t)l * D + k) * (2 * D) + n];
    }
    {
        int e = rem & 7, lane = (rem >> 3) & 63, kk = (rem >> 9) & 7, cb = rem >> 12;
        int n = cb * 16 + (lane & 15);
        int k = kk * 32 + (lane >> 4) * 8 + e;
        w2f[idx] = (f16)W2[((size_t)l * 2 * D + k) * D + n];
    }
}

// ---------------- model kernels ----------------

__global__ void embed_kernel(const int* __restrict__ x, const float* __restrict__ emb,
                             f16* __restrict__ h_h) {
    int idx = blockIdx.x * blockDim.x + threadIdx.x;  // one 8-elem chunk
    if (idx >= N_NODES * (D / 8)) return;
    int n = idx >> 4;   // D/8 = 16
    int d8 = idx & 15;
    const float* e = emb + x[n] * D + d8 * 8;
    f16x8 v;
#pragma unroll
    for (int j = 0; j < 8; ++j) v[j] = (f16)e[j];
    *(f16x8*)(h_h + (size_t)n * D + d8 * 8) = v;
}

// pull aggregation: agg_h[n] = (f16)( h_h[n] + sum_{s in in(n)} h_h[s] ), fp32 accum.
// One wave per node; 4 edge-groups x 16 lanes; 16B/lane loads (1KB per wave-load, 4 edges).
__global__ __launch_bounds__(256) void agg_kernel(const int* __restrict__ offsets,
                                                  const int* __restrict__ sorted_src,
                                                  const f16* __restrict__ h_h,
                                                  f16* __restrict__ agg_h) {
    int node = blockIdx.x * 4 + (threadIdx.x >> 6);
    if (node >= N_NODES) return;
    const int lane = threadIdx.x & 63;
    const int g = lane >> 4;   // edge subgroup 0..3
    const int c = lane & 15;   // 16B chunk of the row

    float acc[8];
    {   // self loop, counted once (group 0 only)
        f16x8 sv = {};
        if (g == 0) sv = *(const f16x8*)(h_h + (size_t)node * D + c * 8);
#pragma unroll
        for (int k = 0; k < 8; ++k) acc[k] = (float)sv[k];
    }

    const int begin = offsets[node], end = offsets[node + 1];
    for (int j = begin + g; j < end; j += 4) {
        int s = sorted_src[j];
        f16x8 v = *(const f16x8*)(h_h + (size_t)s * D + c * 8);
#pragma unroll
        for (int k = 0; k < 8; ++k) acc[k] += (float)v[k];
    }

    // sum the 4 groups (lanes sharing c): xor 16 then 32
#pragma unroll
    for (int k = 0; k < 8; ++k) {
        acc[k] += __shfl_xor(acc[k], 16, 64);
        acc[k] += __shfl_xor(acc[k], 32, 64);
    }
    if (g == 0) {
        f16x8 o;
#pragma unroll
        for (int k = 0; k < 8; ++k) o[k] = (f16)acc[k];
        *(f16x8*)(agg_h + (size_t)node * D + c * 8) = o;
    }
}

__device__ __forceinline__ void gload_lds16(const void* g, void* l) {
    __builtin_amdgcn_global_load_lds((const __attribute__((address_space(1))) void*)g,
                                     (__attribute__((address_space(3))) void*)l, 16, 0, 0);
}

// Fused GIN MLP: z2 = (relu(agg @ W1 + b1)) @ W2 + b2 (stored f16), block-partial column
// stats (sum, sumsq) written contiguously to partial[blockIdx][256] — NO global atomics.
__global__ __launch_bounds__(256) void fused_mlp(const f16* __restrict__ A,
                                                 const f16* __restrict__ w1f,
                                                 const float* __restrict__ b1,
                                                 const f16* __restrict__ w2f,
                                                 const float* __restrict__ b2,
                                                 f16* __restrict__ z2h,
                                                 float* __restrict__ partial) {
    __shared__ __align__(16) char smem[32768 + 1024];
    f16* As = (f16*)smem;                   // 64 x 128 halfs, swizzled (16 KB), aliased by z1s
    f16* z1s = (f16*)smem;                  // 64 x 256 halfs, swizzled (32 KB)
    float* sred = (float*)(smem + 32768);   // 256 f32

    const int tid = threadIdx.x;
    const int r0 = blockIdx.x * 64;
    const int lane = tid & 63;
    const int wave = tid >> 6;
    const int wr = wave >> 1, wc = wave & 1;
    const int l15 = lane & 15, l4 = lane >> 4;

    for (int i = tid; i < 256; i += 256) sred[i] = 0.f;

    // ---- stage A tile: global_load_lds, linear LDS dest + pre-swizzled global source ----
#pragma unroll
    for (int it = 0; it < 4; ++it) {
        const int idx = it * 256 + tid;
        const int row = idx >> 4, c = idx & 15;
        const char* gsrc = (const char*)(A + (size_t)(r0 + row) * D) + ((c * 16) ^ ((row & 7) << 4));
        gload_lds16(gsrc, (char*)As + idx * 16);
    }
    __syncthreads();

    // ---- stage 1: z1^T via mfma(W1, A). lane holds z1[m=l15][n=cf*16+l4*4+j] ----
    f32x4 acc1[2][8] = {};
#pragma unroll
    for (int kk = 0; kk < 4; ++kk) {
        f16x8 afr[2];
#pragma unroll
        for (int fm = 0; fm < 2; ++fm) {
            const int m = wr * 32 + fm * 16 + l15;
            const int byte = ((m * D + kk * 32 + l4 * 8) * 2) ^ ((m & 7) << 4);
            afr[fm] = *(const f16x8*)((const char*)As + byte);
        }
#pragma unroll
        for (int cf = 0; cf < 8; ++cf) {
            f16x8 w = *(const f16x8*)(w1f + ((((wc * 8 + cf) * 4) + kk) * 64 + lane) * 8);
#pragma unroll
            for (int fm = 0; fm < 2; ++fm)
                acc1[fm][cf] = __builtin_amdgcn_mfma_f32_16x16x32_f16(w, afr[fm], acc1[fm][cf], 0, 0, 0);
        }
    }
    __syncthreads();  // all As reads complete before overwriting with z1s

    // ---- epilogue 1: bias + relu -> f16 -> z1s (contiguous 8B writes, swizzled) ----
#pragma unroll
    for (int fm = 0; fm < 2; ++fm) {
        const int m = wr * 32 + fm * 16 + l15;
#pragma unroll
        for (int cf = 0; cf < 8; ++cf) {
            const int n = wc * 128 + cf * 16 + l4 * 4;
            const float4 bb = *(const float4*)(b1 + n);
            f16x4 v;
            v[0] = (f16)fmaxf(acc1[fm][cf][0] + bb.x, 0.f);
            v[1] = (f16)fmaxf(acc1[fm][cf][1] + bb.y, 0.f);
            v[2] = (f16)fmaxf(acc1[fm][cf][2] + bb.z, 0.f);
            v[3] = (f16)fmaxf(acc1[fm][cf][3] + bb.w, 0.f);
            const int byte = ((m * 256 + n) * 2) ^ ((m & 7) << 4);
            *(f16x4*)((char*)z1s + byte) = v;
        }
    }
    __syncthreads();

    // ---- stage 2: z2 = z1 @ W2 (non-swapped), 2x4 frags per wave ----
    f32x4 acc2[2][4] = {};
#pragma unroll
    for (int kk = 0; kk < 8; ++kk) {
        f16x8 afr[2];
#pragma unroll
        for (int fm = 0; fm < 2; ++fm) {
            const int m = wr * 32 + fm * 16 + l15;
            const int byte = ((m * 256 + kk * 32 + l4 * 8) * 2) ^ ((m & 7) << 4);
            afr[fm] = *(const f16x8*)((const char*)z1s + byte);
        }
#pragma unroll
        for (int cf = 0; cf < 4; ++cf) {
            f16x8 w = *(const f16x8*)(w2f + ((((wc * 4 + cf) * 8) + kk) * 64 + lane) * 8);
#pragma unroll
            for (int fm = 0; fm < 2; ++fm)
                acc2[fm][cf] = __builtin_amdgcn_mfma_f32_16x16x32_f16(afr[fm], w, acc2[fm][cf], 0, 0, 0);
        }
    }

    // ---- epilogue 2: bias, store f16, column partial stats ----
    float bv[4];
#pragma unroll
    for (int cf = 0; cf < 4; ++cf) bv[cf] = b2[wc * 64 + cf * 16 + l15];

    float cs[4], cq[4];
#pragma unroll
    for (int cf = 0; cf < 4; ++cf) { cs[cf] = 0.f; cq[cf] = 0.f; }
#pragma unroll
    for (int fm = 0; fm < 2; ++fm)
#pragma unroll
        for (int cf = 0; cf < 4; ++cf) {
            const int col = wc * 64 + cf * 16 + l15;
#pragma unroll
            for (int j = 0; j < 4; ++j) {
                const int row = r0 + wr * 32 + fm * 16 + l4 * 4 + j;
                if (row < N_NODES) {
                    float z = acc2[fm][cf][j] + bv[cf];
                    z2h[(size_t)row * D + col] = (f16)z;
                    cs[cf] += z;
                    cq[cf] += z * z;
                }
            }
        }
#pragma unroll
    for (int cf = 0; cf < 4; ++cf) {
        float s = cs[cf], q = cq[cf];
        s += __shfl_xor(s, 16, 64);
        q += __shfl_xor(q, 16, 64);
        s += __shfl_xor(s, 32, 64);
        q += __shfl_xor(q, 32, 64);
        if (l4 == 0) {
            const int col = wc * 64 + cf * 16 + l15;
            atomicAdd(&sred[col], s);        // LDS atomics only (4 waves)
            atomicAdd(&sred[D + col], q);
        }
    }
    __syncthreads();
    // contiguous, contention-free partial write (1 KB per block)
    for (int i = tid; i < 256; i += 256) partial[(size_t)blockIdx.x * 256 + i] = sred[i];
}

// stage-1 stats reduce: partial2[b][c] = sum_{r = b, b+NB, ...} partial[r][c]  (32 blocks)
__global__ __launch_bounds__(256) void reduce1_kernel(const float* __restrict__ partial,
                                                      float* __restrict__ partial2) {
    const int c = threadIdx.x;
    const int b = blockIdx.x;
    float s = 0.f;
    for (int r = b; r < GX_BLOCKS; r += NB_RED) s += partial[(size_t)r * 256 + c];
    partial2[(size_t)b * 256 + c] = s;
}

// stage-2 stats reduce: stats[c] = sum_b partial2[b][c]  (1 block, 32 rows)
__global__ __launch_bounds__(256) void reduce2_kernel(const float* __restrict__ partial2,
                                                      float* __restrict__ stats) {
    const int c = threadIdx.x;
    float s = 0.f;
#pragma unroll
    for (int r = 0; r < NB_RED; ++r) s += partial2[(size_t)r * 256 + c];
    stats[c] = s;
}

// BatchNorm (training stats); !LAST: relu -> h_h (f16). LAST: no relu -> h (f32, d_out).
template <bool LAST>
__global__ void bn_kernel(const f16* __restrict__ z, const float* __restrict__ stats,
                          const float* __restrict__ gamma, const float* __restrict__ beta,
                          float* __restrict__ hout, f16* __restrict__ h_h) {
    int idx = blockIdx.x * blockDim.x + threadIdx.x;  // one f16x4 chunk
    if (idx >= N_NODES * (D / 4)) return;
    int d4 = idx & 31;
    f16x4 zv = *(const f16x4*)(z + (size_t)idx * 4);
    float4 s = *(const float4*)(stats + d4 * 4);
    float4 sq = *(const float4*)(stats + D + d4 * 4);
    float4 g = *(const float4*)(gamma + d4 * 4);
    float4 b = *(const float4*)(beta + d4 * 4);
    const float invN = 1.0f / (float)N_NODES;
    float ss[4] = {s.x, s.y, s.z, s.w};
    float qq[4] = {sq.x, sq.y, sq.z, sq.w};
    float gg[4] = {g.x, g.y, g.z, g.w};
    float bb[4] = {b.x, b.y, b.z, b.w};
    float o[4];
#pragma unroll
    for (int j = 0; j < 4; ++j) {
        float m = ss[j] * invN;
        float var = qq[j] * invN - m * m;
        float r = rsqrtf(var + EPS);
        o[j] = gg[j] * ((float)zv[j] - m) * r + bb[j];
    }
    if constexpr (LAST) {
        *(float4*)(hout + (size_t)idx * 4) = make_float4(o[0], o[1], o[2], o[3]);
    } else {
        f16x4 v;
#pragma unroll
        for (int j = 0; j < 4; ++j) v[j] = (f16)fmaxf(o[j], 0.f);
        *(f16x4*)(h_h + (size_t)idx * 4) = v;
    }
}

extern "C" void kernel_launch(void* const* d_in, const int* in_sizes, int n_in,
                              void* d_out, int out_size, void* d_ws, size_t ws_size,
                              hipStream_t stream) {
    const int* x_nodes = (const int*)d_in[0];
    const int* src = (const int*)d_in[1];
    const int* dst = (const int*)d_in[2];
    const float* emb = (const float*)d_in[3];
    const float* W1 = (const float*)d_in[4];
    const float* b1 = (const float*)d_in[5];
    const float* W2 = (const float*)d_in[6];
    const float* b2 = (const float*)d_in[7];
    const float* gamma = (const float*)d_in[8];
    const float* beta = (const float*)d_in[9];

    float* h = (float*)d_out;  // final fp32 output

    // workspace layout
    f16* z2h = (f16*)d_ws;                                      // N*D f16
    f16* agg_h = z2h + (size_t)N_NODES * D;                     // N*D f16
    f16* h_h = agg_h + (size_t)N_NODES * D;                     // N*D f16
    f16* w1f = h_h + (size_t)N_NODES * D;                       // L*32768 f16
    f16* w2f = w1f + (size_t)NLAYERS * 2 * D * D;               // L*32768 f16
    float* stats = (float*)(w2f + (size_t)NLAYERS * 2 * D * D); // 256 f32
    float* partial = stats + 256;                               // GX_BLOCKS*256 f32
    float* partial2 = partial + (size_t)GX_BLOCKS * 256;        // NB_RED*256 f32
    int* deg = (int*)(partial2 + (size_t)NB_RED * 256);         // N
    int* offsets = deg + N_NODES;                               // N+1
    int* cursor = offsets + N_NODES + 1;                        // N
    int* blocksums = cursor + N_NODES;                          // 64
    int* sorted_src = blocksums + 64;                           // E

    dim3 blk(256);
    const int nb_scan = (N_NODES + 1023) / 1024;  // 49
    const int nb_edge = (N_EDGES + 255) / 256;

    // ---- one-time per call: weights + CSR ----
    convert_w_kernel<<<(NLAYERS * 32768 + 255) / 256, blk, 0, stream>>>(W1, W2, w1f, w2f);
    hipMemsetAsync(deg, 0, N_NODES * sizeof(int), stream);
    deg_kernel<<<nb_edge, blk, 0, stream>>>(dst, deg);
    scan_block_kernel<<<nb_scan, 1024, 0, stream>>>(deg, offsets, blocksums);
    scan_sums_kernel<<<1, 64, 0, stream>>>(blocksums, nb_scan, offsets);
    scan_add_kernel<<<nb_scan, 1024, 0, stream>>>(offsets, blocksums);
    hipMemcpyAsync(cursor, offsets, N_NODES * sizeof(int), hipMemcpyDeviceToDevice, stream);
    scatter_kernel<<<nb_edge, blk, 0, stream>>>(src, dst, cursor, sorted_src);

    // ---- model ----
    embed_kernel<<<(N_NODES * 16 + 255) / 256, blk, 0, stream>>>(x_nodes, emb, h_h);

    for (int l = 0; l < NLAYERS; ++l) {
        agg_kernel<<<(N_NODES + 3) / 4, blk, 0, stream>>>(offsets, sorted_src, h_h, agg_h);
        fused_mlp<<<GX_BLOCKS, blk, 0, stream>>>(agg_h, w1f + (size_t)l * 32768, b1 + l * 2 * D,
                                                 w2f + (size_t)l * 32768, b2 + l * D, z2h, partial);
        reduce1_kernel<<<NB_RED, blk, 0, stream>>>(partial, partial2);
        reduce2_kernel<<<1, blk, 0, stream>>>(partial2, stats);
        if (l < NLAYERS - 1) {
            bn_kernel<false><<<(N_NODES * 32 + 255) / 256, blk, 0, stream>>>(
                z2h, stats, gamma + l * D, beta + l * D, nullptr, h_h);
        } else {
            bn_kernel<true><<<(N_NODES * 32 + 255) / 256, blk, 0, stream>>>(
                z2h, stats, gamma + l * D, beta + l * D, h, nullptr);
        }
    }
    (void)in_sizes; (void)n_in; (void)out_size; (void)ws_size;
}

// Round 7
// 448.475 us; speedup vs baseline: 1.5022x; 1.0138x over previous
//
#include <hip/hip_runtime.h>

#define N_NODES 50000
#define N_EDGES 600000
#define D 128
#define NLAYERS 5
#define EPS 1e-5f
#define GX_BLOCKS 782  // (N_NODES + 63) / 64
#define NB_RED 32      // stage-1 reduce blocks

typedef _Float16 f16;
typedef f16 f16x8 __attribute__((ext_vector_type(8)));
typedef f16 f16x4 __attribute__((ext_vector_type(4)));
typedef f16 f16x2 __attribute__((ext_vector_type(2)));
typedef float f32x4 __attribute__((ext_vector_type(4)));

// ---------------- CSR build ----------------

__global__ void deg_kernel(const int* __restrict__ dst, int* __restrict__ deg) {
    int e = blockIdx.x * blockDim.x + threadIdx.x;
    if (e < N_EDGES) atomicAdd(&deg[dst[e]], 1);
}

__global__ __launch_bounds__(1024) void scan_block_kernel(const int* __restrict__ deg,
                                                          int* __restrict__ offsets,
                                                          int* __restrict__ blocksums) {
    __shared__ int tmp[1024];
    int i = blockIdx.x * 1024 + threadIdx.x;
    int v = (i < N_NODES) ? deg[i] : 0;
    tmp[threadIdx.x] = v;
    __syncthreads();
#pragma unroll
    for (int off = 1; off < 1024; off <<= 1) {
        int t = (threadIdx.x >= off) ? tmp[threadIdx.x - off] : 0;
        __syncthreads();
        tmp[threadIdx.x] += t;
        __syncthreads();
    }
    if (i < N_NODES) offsets[i] = tmp[threadIdx.x] - v;  // exclusive
    if (threadIdx.x == 1023) blocksums[blockIdx.x] = tmp[1023];
}

__global__ void scan_sums_kernel(int* __restrict__ blocksums, int nb, int* __restrict__ offsets) {
    if (threadIdx.x == 0 && blockIdx.x == 0) {
        int run = 0;
        for (int i = 0; i < nb; ++i) {
            int t = blocksums[i];
            blocksums[i] = run;
            run += t;
        }
        offsets[N_NODES] = N_EDGES;
    }
}

// also initializes cursor = offsets (saves the d2d memcpy launch)
__global__ __launch_bounds__(1024) void scan_add_kernel(int* __restrict__ offsets,
                                                        const int* __restrict__ blocksums,
                                                        int* __restrict__ cursor) {
    int i = blockIdx.x * 1024 + threadIdx.x;
    if (i < N_NODES) {
        int v = offsets[i] + blocksums[blockIdx.x];
        offsets[i] = v;
        cursor[i] = v;
    }
}

__global__ void scatter_kernel(const int* __restrict__ src, const int* __restrict__ dst,
                               int* __restrict__ cursor, int* __restrict__ sorted_src) {
    int e = blockIdx.x * blockDim.x + threadIdx.x;
    if (e >= N_EDGES) return;
    int t = dst[e];
    int pos = atomicAdd(&cursor[t], 1);
    sorted_src[pos] = src[e];
}

// ---------------- weight convert to MFMA fragment order ----------------
// w1f: per layer [cb=16][kk=4][lane=64][e=8];  n = cb*16+(lane&15), k = kk*32+(lane>>4)*8+e
// w2f: per layer [cb=8 ][kk=8][lane=64][e=8];  n = cb*16+(lane&15), k = kk*32+(lane>>4)*8+e
__global__ void convert_w_kernel(const float* __restrict__ W1, const float* __restrict__ W2,
                                 f16* __restrict__ w1f, f16* __restrict__ w2f) {
    int idx = blockIdx.x * blockDim.x + threadIdx.x;
    if (idx >= NLAYERS * 32768) return;
    int l = idx >> 15, rem = idx & 32767;
    {
        int e = rem & 7, lane = (rem >> 3) & 63, kk = (rem >> 9) & 3, cb = rem >> 11;
        int n = cb * 16 + (lane & 15);
        int k = kk * 32 + (lane >> 4) * 8 + e;
        w1f[idx] = (f16)W1[((size_t)l * D + k) * (2 * D) + n];
    }
    {
        int e = rem & 7, lane = (rem >> 3) & 63, kk = (rem >> 9) & 7, cb = rem >> 12;
        int n = cb * 16 + (lane & 15);
        int k = kk * 32 + (lane >> 4) * 8 + e;
        w2f[idx] = (f16)W2[((size_t)l * 2 * D + k) * D + n];
    }
}

// ---------------- model kernels ----------------

// pull aggregation with fused producer transform; fp32 accumulate, f16 output.
// MODE 0: source row s = emb[x[s]]               (layer 0; embeds on the fly)
// MODE 1: source row s = relu(scale*z2h[s]+shift) (BN+relu of previous layer fused)
// One wave per node; 4 edge-groups x 16 lanes; 16B(f16)/32B(f32) per lane.
template <int MODE>
__global__ __launch_bounds__(256) void agg_kernel(const int* __restrict__ offsets,
                                                  const int* __restrict__ sorted_src,
                                                  const f16* __restrict__ z2h,
                                                  const int* __restrict__ x,
                                                  const float* __restrict__ emb,
                                                  const float* __restrict__ ss,
                                                  f16* __restrict__ agg_h) {
    int node = blockIdx.x * 4 + (threadIdx.x >> 6);
    if (node >= N_NODES) return;
    const int lane = threadIdx.x & 63;
    const int g = lane >> 4;   // edge subgroup 0..3
    const int c = lane & 15;   // chunk of the row (8 elems)

    float scale[8], shift[8];
    if constexpr (MODE == 1) {
        *(float4*)&scale[0] = *(const float4*)(ss + c * 8);
        *(float4*)&scale[4] = *(const float4*)(ss + c * 8 + 4);
        *(float4*)&shift[0] = *(const float4*)(ss + 128 + c * 8);
        *(float4*)&shift[4] = *(const float4*)(ss + 128 + c * 8 + 4);
    }

    float acc[8];
    if (g == 0) {  // self loop, counted once
        if constexpr (MODE == 0) {
            const float* e = emb + x[node] * D + c * 8;
            float4 a0 = *(const float4*)e;
            float4 a1 = *(const float4*)(e + 4);
            acc[0] = a0.x; acc[1] = a0.y; acc[2] = a0.z; acc[3] = a0.w;
            acc[4] = a1.x; acc[5] = a1.y; acc[6] = a1.z; acc[7] = a1.w;
        } else {
            f16x8 v = *(const f16x8*)(z2h + (size_t)node * D + c * 8);
#pragma unroll
            for (int k = 0; k < 8; ++k) acc[k] = fmaxf(scale[k] * (float)v[k] + shift[k], 0.f);
        }
    } else {
#pragma unroll
        for (int k = 0; k < 8; ++k) acc[k] = 0.f;
    }

    const int begin = offsets[node], end = offsets[node + 1];
    for (int j = begin + g; j < end; j += 4) {
        int s = sorted_src[j];
        if constexpr (MODE == 0) {
            const float* e = emb + x[s] * D + c * 8;
            float4 a0 = *(const float4*)e;
            float4 a1 = *(const float4*)(e + 4);
            acc[0] += a0.x; acc[1] += a0.y; acc[2] += a0.z; acc[3] += a0.w;
            acc[4] += a1.x; acc[5] += a1.y; acc[6] += a1.z; acc[7] += a1.w;
        } else {
            f16x8 v = *(const f16x8*)(z2h + (size_t)s * D + c * 8);
#pragma unroll
            for (int k = 0; k < 8; ++k) acc[k] += fmaxf(scale[k] * (float)v[k] + shift[k], 0.f);
        }
    }

    // sum the 4 groups (lanes sharing c)
#pragma unroll
    for (int k = 0; k < 8; ++k) {
        acc[k] += __shfl_xor(acc[k], 16, 64);
        acc[k] += __shfl_xor(acc[k], 32, 64);
    }
    if (g == 0) {
        f16x8 o;
#pragma unroll
        for (int k = 0; k < 8; ++k) o[k] = (f16)acc[k];
        *(f16x8*)(agg_h + (size_t)node * D + c * 8) = o;
    }
}

__device__ __forceinline__ void gload_lds16(const void* g, void* l) {
    __builtin_amdgcn_global_load_lds((const __attribute__((address_space(1))) void*)g,
                                     (__attribute__((address_space(3))) void*)l, 16, 0, 0);
}

// Fused GIN MLP: z2 = (relu(agg @ W1 + b1)) @ W2 + b2 (stored f16), block-partial column
// stats (sum, sumsq) written contiguously to partial[blockIdx][256] — NO global atomics.
__global__ __launch_bounds__(256) void fused_mlp(const f16* __restrict__ A,
                                                 const f16* __restrict__ w1f,
                                                 const float* __restrict__ b1,
                                                 const f16* __restrict__ w2f,
                                                 const float* __restrict__ b2,
                                                 f16* __restrict__ z2h,
                                                 float* __restrict__ partial) {
    __shared__ __align__(16) char smem[32768 + 1024];
    f16* As = (f16*)smem;                   // 64 x 128 halfs, swizzled (16 KB), aliased by z1s
    f16* z1s = (f16*)smem;                  // 64 x 256 halfs, swizzled (32 KB)
    float* sred = (float*)(smem + 32768);   // 256 f32

    const int tid = threadIdx.x;
    const int r0 = blockIdx.x * 64;
    const int lane = tid & 63;
    const int wave = tid >> 6;
    const int wr = wave >> 1, wc = wave & 1;
    const int l15 = lane & 15, l4 = lane >> 4;

    for (int i = tid; i < 256; i += 256) sred[i] = 0.f;

    // ---- stage A tile: global_load_lds, linear LDS dest + pre-swizzled global source ----
#pragma unroll
    for (int it = 0; it < 4; ++it) {
        const int idx = it * 256 + tid;
        const int row = idx >> 4, c = idx & 15;
        const char* gsrc = (const char*)(A + (size_t)(r0 + row) * D) + ((c * 16) ^ ((row & 7) << 4));
        gload_lds16(gsrc, (char*)As + idx * 16);
    }
    __syncthreads();

    // ---- stage 1: z1^T via mfma(W1, A). lane holds z1[m=l15][n=cf*16+l4*4+j] ----
    f32x4 acc1[2][8] = {};
#pragma unroll
    for (int kk = 0; kk < 4; ++kk) {
        f16x8 afr[2];
#pragma unroll
        for (int fm = 0; fm < 2; ++fm) {
            const int m = wr * 32 + fm * 16 + l15;
            const int byte = ((m * D + kk * 32 + l4 * 8) * 2) ^ ((m & 7) << 4);
            afr[fm] = *(const f16x8*)((const char*)As + byte);
        }
#pragma unroll
        for (int cf = 0; cf < 8; ++cf) {
            f16x8 w = *(const f16x8*)(w1f + ((((wc * 8 + cf) * 4) + kk) * 64 + lane) * 8);
#pragma unroll
            for (int fm = 0; fm < 2; ++fm)
                acc1[fm][cf] = __builtin_amdgcn_mfma_f32_16x16x32_f16(w, afr[fm], acc1[fm][cf], 0, 0, 0);
        }
    }
    __syncthreads();  // all As reads complete before overwriting with z1s

    // ---- epilogue 1: bias + relu -> f16 -> z1s (contiguous 8B writes, swizzled) ----
#pragma unroll
    for (int fm = 0; fm < 2; ++fm) {
        const int m = wr * 32 + fm * 16 + l15;
#pragma unroll
        for (int cf = 0; cf < 8; ++cf) {
            const int n = wc * 128 + cf * 16 + l4 * 4;
            const float4 bb = *(const float4*)(b1 + n);
            f16x4 v;
            v[0] = (f16)fmaxf(acc1[fm][cf][0] + bb.x, 0.f);
            v[1] = (f16)fmaxf(acc1[fm][cf][1] + bb.y, 0.f);
            v[2] = (f16)fmaxf(acc1[fm][cf][2] + bb.z, 0.f);
            v[3] = (f16)fmaxf(acc1[fm][cf][3] + bb.w, 0.f);
            const int byte = ((m * 256 + n) * 2) ^ ((m & 7) << 4);
            *(f16x4*)((char*)z1s + byte) = v;
        }
    }
    __syncthreads();

    // ---- stage 2: z2 = z1 @ W2 (non-swapped), 2x4 frags per wave ----
    f32x4 acc2[2][4] = {};
#pragma unroll
    for (int kk = 0; kk < 8; ++kk) {
        f16x8 afr[2];
#pragma unroll
        for (int fm = 0; fm < 2; ++fm) {
            const int m = wr * 32 + fm * 16 + l15;
            const int byte = ((m * 256 + kk * 32 + l4 * 8) * 2) ^ ((m & 7) << 4);
            afr[fm] = *(const f16x8*)((const char*)z1s + byte);
        }
#pragma unroll
        for (int cf = 0; cf < 4; ++cf) {
            f16x8 w = *(const f16x8*)(w2f + ((((wc * 4 + cf) * 8) + kk) * 64 + lane) * 8);
#pragma unroll
            for (int fm = 0; fm < 2; ++fm)
                acc2[fm][cf] = __builtin_amdgcn_mfma_f32_16x16x32_f16(afr[fm], w, acc2[fm][cf], 0, 0, 0);
        }
    }

    // ---- epilogue 2: bias, store f16, column partial stats ----
    float bv[4];
#pragma unroll
    for (int cf = 0; cf < 4; ++cf) bv[cf] = b2[wc * 64 + cf * 16 + l15];

    float cs[4], cq[4];
#pragma unroll
    for (int cf = 0; cf < 4; ++cf) { cs[cf] = 0.f; cq[cf] = 0.f; }
#pragma unroll
    for (int fm = 0; fm < 2; ++fm)
#pragma unroll
        for (int cf = 0; cf < 4; ++cf) {
            const int col = wc * 64 + cf * 16 + l15;
#pragma unroll
            for (int j = 0; j < 4; ++j) {
                const int row = r0 + wr * 32 + fm * 16 + l4 * 4 + j;
                if (row < N_NODES) {
                    float z = acc2[fm][cf][j] + bv[cf];
                    z2h[(size_t)row * D + col] = (f16)z;
                    cs[cf] += z;
                    cq[cf] += z * z;
                }
            }
        }
#pragma unroll
    for (int cf = 0; cf < 4; ++cf) {
        float s = cs[cf], q = cq[cf];
        s += __shfl_xor(s, 16, 64);
        q += __shfl_xor(q, 16, 64);
        s += __shfl_xor(s, 32, 64);
        q += __shfl_xor(q, 32, 64);
        if (l4 == 0) {
            const int col = wc * 64 + cf * 16 + l15;
            atomicAdd(&sred[col], s);        // LDS atomics only (4 waves)
            atomicAdd(&sred[D + col], q);
        }
    }
    __syncthreads();
    for (int i = tid; i < 256; i += 256) partial[(size_t)blockIdx.x * 256 + i] = sred[i];
}

// stage-1 stats reduce: partial2[b][c] = sum_{r = b, b+NB, ...} partial[r][c]  (32 blocks)
__global__ __launch_bounds__(256) void reduce1_kernel(const float* __restrict__ partial,
                                                      float* __restrict__ partial2) {
    const int c = threadIdx.x;
    const int b = blockIdx.x;
    float s = 0.f;
    for (int r = b; r < GX_BLOCKS; r += NB_RED) s += partial[(size_t)r * 256 + c];
    partial2[(size_t)b * 256 + c] = s;
}

// stage-2: finish stats and emit BN affine form: ss[c]=scale, ss[128+c]=shift
__global__ __launch_bounds__(256) void reduce2_kernel(const float* __restrict__ partial2,
                                                      const float* __restrict__ gamma,
                                                      const float* __restrict__ beta,
                                                      float* __restrict__ ss) {
    __shared__ float st[256];
    const int c = threadIdx.x;
    float s = 0.f;
#pragma unroll
    for (int r = 0; r < NB_RED; ++r) s += partial2[(size_t)r * 256 + c];
    st[c] = s;
    __syncthreads();
    if (c < 128) {
        const float invN = 1.0f / (float)N_NODES;
        float mean = st[c] * invN;
        float var = st[128 + c] * invN - mean * mean;
        float sc = gamma[c] * rsqrtf(var + EPS);
        ss[c] = sc;
        ss[128 + c] = beta[c] - mean * sc;
    }
}

// final-layer BN (no relu), f32 output to d_out
__global__ void bn_last_kernel(const f16* __restrict__ z, const float* __restrict__ ss,
                               float* __restrict__ hout) {
    int idx = blockIdx.x * blockDim.x + threadIdx.x;  // one 8-elem chunk
    if (idx >= N_NODES * (D / 8)) return;
    int d8 = idx & 15;
    f16x8 v = *(const f16x8*)(z + (size_t)idx * 8);
    float4 s0 = *(const float4*)(ss + d8 * 8);
    float4 s1 = *(const float4*)(ss + d8 * 8 + 4);
    float4 t0 = *(const float4*)(ss + 128 + d8 * 8);
    float4 t1 = *(const float4*)(ss + 128 + d8 * 8 + 4);
    float4 o0, o1;
    o0.x = s0.x * (float)v[0] + t0.x;
    o0.y = s0.y * (float)v[1] + t0.y;
    o0.z = s0.z * (float)v[2] + t0.z;
    o0.w = s0.w * (float)v[3] + t0.w;
    o1.x = s1.x * (float)v[4] + t1.x;
    o1.y = s1.y * (float)v[5] + t1.y;
    o1.z = s1.z * (float)v[6] + t1.z;
    o1.w = s1.w * (float)v[7] + t1.w;
    *(float4*)(hout + (size_t)idx * 8) = o0;
    *(float4*)(hout + (size_t)idx * 8 + 4) = o1;
}

extern "C" void kernel_launch(void* const* d_in, const int* in_sizes, int n_in,
                              void* d_out, int out_size, void* d_ws, size_t ws_size,
                              hipStream_t stream) {
    const int* x_nodes = (const int*)d_in[0];
    const int* src = (const int*)d_in[1];
    const int* dst = (const int*)d_in[2];
    const float* emb = (const float*)d_in[3];
    const float* W1 = (const float*)d_in[4];
    const float* b1 = (const float*)d_in[5];
    const float* W2 = (const float*)d_in[6];
    const float* b2 = (const float*)d_in[7];
    const float* gamma = (const float*)d_in[8];
    const float* beta = (const float*)d_in[9];

    float* h = (float*)d_out;  // final fp32 output

    // workspace layout
    f16* z2h = (f16*)d_ws;                                      // N*D f16
    f16* agg_h = z2h + (size_t)N_NODES * D;                     // N*D f16
    f16* w1f = agg_h + (size_t)N_NODES * D;                     // L*32768 f16
    f16* w2f = w1f + (size_t)NLAYERS * 2 * D * D;               // L*32768 f16
    float* ss = (float*)(w2f + (size_t)NLAYERS * 2 * D * D);    // 256 f32 (scale|shift)
    float* partial = ss + 256;                                  // GX_BLOCKS*256 f32
    float* partial2 = partial + (size_t)GX_BLOCKS * 256;        // NB_RED*256 f32
    int* deg = (int*)(partial2 + (size_t)NB_RED * 256);         // N
    int* offsets = deg + N_NODES;                               // N+1
    int* cursor = offsets + N_NODES + 1;                        // N
    int* blocksums = cursor + N_NODES;                          // 64
    int* sorted_src = blocksums + 64;                           // E

    dim3 blk(256);
    const int nb_scan = (N_NODES + 1023) / 1024;  // 49
    const int nb_edge = (N_EDGES + 255) / 256;

    // ---- one-time per call: weights + CSR ----
    convert_w_kernel<<<(NLAYERS * 32768 + 255) / 256, blk, 0, stream>>>(W1, W2, w1f, w2f);
    hipMemsetAsync(deg, 0, N_NODES * sizeof(int), stream);
    deg_kernel<<<nb_edge, blk, 0, stream>>>(dst, deg);
    scan_block_kernel<<<nb_scan, 1024, 0, stream>>>(deg, offsets, blocksums);
    scan_sums_kernel<<<1, 64, 0, stream>>>(blocksums, nb_scan, offsets);
    scan_add_kernel<<<nb_scan, 1024, 0, stream>>>(offsets, blocksums, cursor);
    scatter_kernel<<<nb_edge, blk, 0, stream>>>(src, dst, cursor, sorted_src);

    // ---- model: per layer {agg (fused BN+relu of prev), MLP, stats reduce} ----
    const int agg_gx = (N_NODES + 3) / 4;
    for (int l = 0; l < NLAYERS; ++l) {
        if (l == 0) {
            agg_kernel<0><<<agg_gx, blk, 0, stream>>>(offsets, sorted_src, nullptr,
                                                      x_nodes, emb, nullptr, agg_h);
        } else {
            agg_kernel<1><<<agg_gx, blk, 0, stream>>>(offsets, sorted_src, z2h,
                                                      nullptr, nullptr, ss, agg_h);
        }
        fused_mlp<<<GX_BLOCKS, blk, 0, stream>>>(agg_h, w1f + (size_t)l * 32768, b1 + l * 2 * D,
                                                 w2f + (size_t)l * 32768, b2 + l * D, z2h, partial);
        reduce1_kernel<<<NB_RED, blk, 0, stream>>>(partial, partial2);
        reduce2_kernel<<<1, blk, 0, stream>>>(partial2, gamma + l * D, beta + l * D, ss);
    }
    bn_last_kernel<<<(N_NODES * 16 + 255) / 256, blk, 0, stream>>>(z2h, ss, h);
    (void)in_sizes; (void)n_in; (void)out_size; (void)ws_size;
}